// Round 10
// baseline (117.455 us; speedup 1.0000x reference)
//
#include <hip/hip_runtime.h>
#include <stdint.h>

#define T_TOK 8192
#define DD 1024
#define OO 1024
#define EE 8
#define CAP 8192
#define BM 64
#define BN 128
#define BK 64

typedef __attribute__((ext_vector_type(8))) short short8;
typedef __attribute__((ext_vector_type(4))) float f32x4;

__device__ __forceinline__ unsigned short f2b(float f){
  union { float f; unsigned u; } v; v.f = f;
  unsigned r = v.u + 0x7FFFu + ((v.u >> 16) & 1u);
  return (unsigned short)(r >> 16);
}
__device__ __forceinline__ float b2f(unsigned short us){
  union { unsigned u; float f; } v; v.u = ((unsigned)us) << 16; return v.f;
}

__device__ __forceinline__ void gld16(const void* g, void* l){
  __builtin_amdgcn_global_load_lds(
      (const __attribute__((address_space(1))) unsigned int*)g,
      (__attribute__((address_space(3))) unsigned int*)l,
      16, 0, 0);
}

// ---------------- phase 0b: expert_w [e][d][o] f32 -> Wt [e][o][d] bf16 ----------------
__global__ __launch_bounds__(256) void transp_kernel(const float* __restrict__ w,
                                                     unsigned short* __restrict__ wt){
  __shared__ float t[32][33];
  const int e = blockIdx.z;
  const int dbase = blockIdx.x * 32;
  const int obase = blockIdx.y * 32;
  const int lx = threadIdx.x & 31, ly = threadIdx.x >> 5;   // 32 x 8
  const float* src = w + ((size_t)e << 20);
  #pragma unroll
  for (int i = 0; i < 4; ++i){
    int d = dbase + ly + i * 8;
    t[ly + i * 8][lx] = src[(size_t)d * OO + obase + lx];
  }
  __syncthreads();
  unsigned short* dst = wt + ((size_t)e << 20);
  #pragma unroll
  for (int i = 0; i < 4; ++i){
    int o = obase + ly + i * 8;
    dst[(size_t)o * DD + dbase + lx] = f2b(t[lx][ly + i * 8]);
  }
}

// ---------------- phase 1a: router logits + top-2 (NO atomics) + fused x->bf16 --------
__global__ __launch_bounds__(256) void router_kernel(
    const float* __restrict__ x, const float* __restrict__ gw, const float* __restrict__ gb,
    int2* __restrict__ e01, float2* __restrict__ w01, unsigned short* __restrict__ xb)
{
  __shared__ float sgw[EE * DD];
  const int tid = threadIdx.x;
  for (int i = tid; i < EE * DD / 4; i += 256)
    ((float4*)sgw)[i] = ((const float4*)gw)[i];
  __syncthreads();
  const int wid = tid >> 6, l = tid & 63;
  const int t = blockIdx.x * 4 + wid;
  double acc[EE];
  #pragma unroll
  for (int e = 0; e < EE; ++e) acc[e] = 0.0;
  const float4* xr = (const float4*)(x + (size_t)t * DD);
  ushort4* xw = (ushort4*)(xb + (size_t)t * DD);
  #pragma unroll
  for (int it = 0; it < 4; ++it){
    float4 xv = xr[it * 64 + l];
    ushort4 r;
    r.x = f2b(xv.x); r.y = f2b(xv.y); r.z = f2b(xv.z); r.w = f2b(xv.w);
    xw[it * 64 + l] = r;                         // fused x -> bf16
    #pragma unroll
    for (int e = 0; e < EE; ++e){
      float4 g = ((const float4*)(sgw + e * DD))[it * 64 + l];
      acc[e] += (double)xv.x * g.x + (double)xv.y * g.y
              + (double)xv.z * g.z + (double)xv.w * g.w;
    }
  }
  #pragma unroll
  for (int off = 32; off > 0; off >>= 1){
    #pragma unroll
    for (int e = 0; e < EE; ++e) acc[e] += __shfl_xor(acc[e], off);
  }
  if (l == 0){
    float lg[EE];
    #pragma unroll
    for (int e = 0; e < EE; ++e) lg[e] = (float)acc[e] + gb[e];
    int e0 = 0; float v0 = lg[0];
    for (int e = 1; e < EE; ++e) if (lg[e] > v0){ v0 = lg[e]; e0 = e; }
    int e1 = -1; float v1 = -3.4e38f;
    for (int e = 0; e < EE; ++e) if (e != e0 && lg[e] > v1){ v1 = lg[e]; e1 = e; }
    float ex = expf(v1 - v0);            // <= 1
    float s = 1.0f + ex;
    e01[t] = make_int2(e0, e1);
    w01[t] = make_float2(1.0f / s, ex / s);
  }
}

// ---------------- phase 1b: per-expert compaction (8 blocks, LDS scan, no atomics) ------
// toks entry = tok*2 + slot (slot: 0 if e is tok's top-1, else 1) = partial-row index.
__global__ __launch_bounds__(256) void compact_kernel(
    const int2* __restrict__ e01,
    int* __restrict__ counts, int* __restrict__ toks)
{
  const int e = blockIdx.x;
  const int tid = threadIdx.x;
  __shared__ int pre[256];
  const int base = tid * (T_TOK / 256);          // 32 tokens/thread, token-ordered
  int c = 0;
  #pragma unroll 4
  for (int i = 0; i < T_TOK / 256; ++i){
    int2 ee = e01[base + i];
    c += (ee.x == e || ee.y == e) ? 1 : 0;
  }
  pre[tid] = c;
  __syncthreads();
  #pragma unroll
  for (int off = 1; off < 256; off <<= 1){
    int add = (tid >= off) ? pre[tid - off] : 0;
    __syncthreads();
    pre[tid] += add;
    __syncthreads();
  }
  int pos = pre[tid] - c;                        // exclusive prefix
  #pragma unroll 4
  for (int i = 0; i < T_TOK / 256; ++i){
    int2 ee = e01[base + i];
    if (ee.x == e || ee.y == e){
      toks[e * CAP + pos] = (base + i) * 2 + (ee.x == e ? 0 : 1);
      ++pos;
    }
  }
  if (tid == 255) counts[e] = pre[255];
}

// ---------------- phase 2: per-expert gathered GEMM -> bf16 partial rows (no atomics) ---
// grid: (nt=8, mt=128, e=8); block 256 (4 waves, 2x2 of 32x64); 24 KB LDS
// BM=64: smaller tile -> ~4-5 resident blocks/CU for latency hiding (r9 theory)
__global__ __launch_bounds__(256, 4) void moe_gemm(
    const unsigned short* __restrict__ xb,     // [T][D] bf16
    const unsigned short* __restrict__ wtr,    // [E][O][D] bf16 (pre-transposed)
    const int* __restrict__ counts,
    const int* __restrict__ toks,              // packed tok*2+slot
    unsigned short* __restrict__ part)         // [2T][O] bf16 raw expert outputs
{
  const int e = blockIdx.z;
  const int cnt = counts[e];
  const int mt = blockIdx.y;
  if (mt * BM >= cnt) return;
  const int nt = blockIdx.x;

  __shared__ __align__(16) unsigned short As[BM * BK];   // 8 KB
  __shared__ __align__(16) unsigned short Bs[BN * BK];   // 16 KB

  const int tid = threadIdx.x;
  const int wid = tid >> 6;
  const int l = tid & 63;
  const int lb = e * CAP;

  const unsigned short* srcA[2];
  const unsigned short* srcB[4];
  #pragma unroll
  for (int i = 0; i < 2; ++i){
    int r = i * 32 + wid * 8 + (l >> 3);          // tile row 0..63
    int c = (l & 7) ^ (r & 7);                    // pre-swizzled source chunk
    int gr = mt * BM + r; if (gr > cnt - 1) gr = cnt - 1;
    int tok = toks[lb + gr] >> 1;
    srcA[i] = xb + (size_t)tok * DD + c * 8;
  }
  #pragma unroll
  for (int i = 0; i < 4; ++i){
    int r = i * 32 + wid * 8 + (l >> 3);          // tile row 0..127
    int c = (l & 7) ^ (r & 7);
    srcB[i] = wtr + ((size_t)e << 20) + (size_t)(nt * BN + r) * DD + c * 8;
  }

  f32x4 acc[2][4];
  #pragma unroll
  for (int m = 0; m < 2; ++m)
    #pragma unroll
    for (int n = 0; n < 4; ++n) acc[m][n] = (f32x4)0.0f;

  const int wr = wid >> 1, wc = wid & 1;
  const int rA = l & 15, hi = l >> 4, x7 = l & 7;
  const char* AsB = (const char*)As;
  const char* BsB = (const char*)Bs;

  for (int kb = 0; kb < DD / BK; ++kb){
    __syncthreads();                              // previous compute done
    #pragma unroll
    for (int i = 0; i < 2; ++i)
      gld16(srcA[i] + kb * BK, As + (i * 32 + wid * 8) * BK);
    #pragma unroll
    for (int i = 0; i < 4; ++i)
      gld16(srcB[i] + kb * BK, Bs + (i * 32 + wid * 8) * BK);
    __syncthreads();                              // drains vmcnt before barrier
    #pragma unroll
    for (int kk = 0; kk < 2; ++kk){
      short8 af[2], bf[4];
      const int ch = ((kk << 2) + hi) ^ x7;       // swizzled read chunk
      #pragma unroll
      for (int m = 0; m < 2; ++m){
        int row = wr * 32 + m * 16 + rA;          // row&7 == l&7
        af[m] = *(const short8*)(AsB + row * (BK * 2) + ch * 16);
      }
      #pragma unroll
      for (int n = 0; n < 4; ++n){
        int orow = wc * 64 + n * 16 + rA;
        bf[n] = *(const short8*)(BsB + orow * (BK * 2) + ch * 16);
      }
      #pragma unroll
      for (int m = 0; m < 2; ++m)
        #pragma unroll
        for (int n = 0; n < 4; ++n)
          acc[m][n] = __builtin_amdgcn_mfma_f32_16x16x32_bf16(af[m], bf[n], acc[m][n], 0, 0, 0);
    }
  }

  // epilogue: plain bf16 stores of raw acc into this entry's partial row
  const int col0 = nt * BN + wc * 64;
  #pragma unroll
  for (int m = 0; m < 2; ++m){
    int rbase = mt * BM + wr * 32 + m * 16 + hi * 4;
    #pragma unroll
    for (int j = 0; j < 4; ++j){
      int rr = rbase + j;
      if (rr < cnt){
        unsigned short* prow = part + (size_t)toks[lb + rr] * OO;
        #pragma unroll
        for (int n = 0; n < 4; ++n)
          prow[col0 + n * 16 + rA] = f2b(acc[m][n][j]);
      }
    }
  }
}

// ---------------- phase 3: combine -> out[t] = w0*(p0+b[e0]) + w1*(p1+b[e1]) ----------
__global__ __launch_bounds__(256) void combine_kernel(
    const unsigned short* __restrict__ part,
    const int2* __restrict__ e01, const float2* __restrict__ w01,
    const float* __restrict__ ebias, float* __restrict__ out)
{
  const int tid = threadIdx.x;
  const int wid = tid >> 6, l = tid & 63;
  const int t = blockIdx.x * 4 + wid;
  const int2 ee = e01[t];
  const float2 ww = w01[t];
  const short8* p0 = (const short8*)(part + ((size_t)t * 2) * OO);
  const short8* p1 = (const short8*)(part + ((size_t)t * 2 + 1) * OO);
  const float4* b0 = (const float4*)(ebias + (size_t)ee.x * OO);
  const float4* b1 = (const float4*)(ebias + (size_t)ee.y * OO);
  float4* o = (float4*)(out + (size_t)t * OO);
  #pragma unroll
  for (int i = 0; i < 2; ++i){
    short8 a = p0[i * 64 + l];
    short8 b = p1[i * 64 + l];
    #pragma unroll
    for (int h = 0; h < 2; ++h){
      int cidx = (i * 64 + l) * 2 + h;
      float4 bb0 = b0[cidx], bb1 = b1[cidx];
      float4 r;
      r.x = ww.x * (b2f((unsigned short)a[h*4+0]) + bb0.x) + ww.y * (b2f((unsigned short)b[h*4+0]) + bb1.x);
      r.y = ww.x * (b2f((unsigned short)a[h*4+1]) + bb0.y) + ww.y * (b2f((unsigned short)b[h*4+1]) + bb1.y);
      r.z = ww.x * (b2f((unsigned short)a[h*4+2]) + bb0.z) + ww.y * (b2f((unsigned short)b[h*4+2]) + bb1.z);
      r.w = ww.x * (b2f((unsigned short)a[h*4+3]) + bb0.w) + ww.y * (b2f((unsigned short)b[h*4+3]) + bb1.w);
      o[cidx] = r;
    }
  }
}

extern "C" void kernel_launch(void* const* d_in, const int* in_sizes, int n_in,
                              void* d_out, int out_size, void* d_ws, size_t ws_size,
                              hipStream_t stream) {
  const float* x     = (const float*)d_in[0];
  const float* gw    = (const float*)d_in[1];
  const float* gb    = (const float*)d_in[2];
  const float* ew    = (const float*)d_in[3];
  const float* ebias = (const float*)d_in[4];
  float* out = (float*)d_out;
  char* ws = (char*)d_ws;

  // layout: [0,1K) counts | [1K..) toks, e01, w01 | 1MB: part 32MB | 33MB: xb 16MB | 49MB: wtr 16MB
  int*    counts = (int*)ws;
  int*    toks   = (int*)(ws + 1024);                          // 256 KB (packed tok*2+slot)
  int2*   e01    = (int2*)(ws + 1024 + EE * CAP * 4);          // 64 KB
  float2* w01    = (float2*)(ws + 1024 + EE * CAP * 4 + T_TOK * 8); // 64 KB
  unsigned short* part = (unsigned short*)(ws + (1 << 20));            // 32 MB
  unsigned short* xb   = (unsigned short*)(ws + (1 << 20) + ((size_t)2 * T_TOK * OO * 2)); // 16 MB
  unsigned short* wtr  = xb + (size_t)T_TOK * DD;                      // 16 MB

  transp_kernel<<<dim3(DD / 32, OO / 32, EE), 256, 0, stream>>>(ew, wtr);
  router_kernel<<<T_TOK / 4, 256, 0, stream>>>(x, gw, gb, e01, w01, xb);
  compact_kernel<<<EE, 256, 0, stream>>>(e01, counts, toks);
  moe_gemm<<<dim3(OO / BN, T_TOK / BM, EE), 256, 0, stream>>>(xb, wtr, counts, toks, part);
  combine_kernel<<<T_TOK / 4, 256, 0, stream>>>(part, e01, w01, ebias, out);
}

// Round 11
// 109.416 us; speedup vs baseline: 1.0735x; 1.0735x over previous
//
#include <hip/hip_runtime.h>
#include <stdint.h>

#define T_TOK 8192
#define DD 1024
#define OO 1024
#define EE 8
#define CAP 8192
#define BM 64
#define BN 128
#define BK 64

typedef __attribute__((ext_vector_type(8))) short short8;
typedef __attribute__((ext_vector_type(4))) float f32x4;

__device__ __forceinline__ unsigned short f2b(float f){
  union { float f; unsigned u; } v; v.f = f;
  unsigned r = v.u + 0x7FFFu + ((v.u >> 16) & 1u);
  return (unsigned short)(r >> 16);
}
__device__ __forceinline__ float b2f(unsigned short us){
  union { unsigned u; float f; } v; v.u = ((unsigned)us) << 16; return v.f;
}

__device__ __forceinline__ void gld16(const void* g, void* l){
  __builtin_amdgcn_global_load_lds(
      (const __attribute__((address_space(1))) unsigned int*)g,
      (__attribute__((address_space(3))) unsigned int*)l,
      16, 0, 0);
}

// ---------------- phase 0b: expert_w [e][d][o] f32 -> Wt [e][o][d] bf16 ----------------
// v2: 64x64 tile, float4 loads, ushort8 stores (G13). grid (16,16,8), 256 thr.
__global__ __launch_bounds__(256) void transp_kernel(const float* __restrict__ w,
                                                     unsigned short* __restrict__ wt){
  __shared__ float t[64][68];                     // 272B rows: 16B-aligned, bank-spread
  const int e = blockIdx.z;
  const int dbase = blockIdx.x * 64;
  const int obase = blockIdx.y * 64;
  const int tid = threadIdx.x;
  const float* src = w + ((size_t)e << 20);

  const int f4c = tid & 15;                       // float4 column: o0 = f4c*4
  const int r0  = tid >> 4;                       // row within shot
  #pragma unroll
  for (int s = 0; s < 4; ++s){
    int d = r0 + s * 16;
    float4 v = *(const float4*)(src + (size_t)(dbase + d) * OO + obase + f4c * 4);
    *(float4*)&t[d][f4c * 4] = v;                 // aligned (272B row stride)
  }
  __syncthreads();

  const int o  = tid >> 2;                        // 0..63
  const int dc = (tid & 3) * 16;                  // d-chunk base
  unsigned short* dst = wt + ((size_t)e << 20) + (size_t)(obase + o) * DD + dbase + dc;
  short8 lo, hi;
  #pragma unroll
  for (int k = 0; k < 8; ++k) lo[k] = (short)f2b(t[dc + k][o]);
  #pragma unroll
  for (int k = 0; k < 8; ++k) hi[k] = (short)f2b(t[dc + 8 + k][o]);
  *(short8*)dst = lo;
  *(short8*)(dst + 8) = hi;
}

// ---------------- phase 1a: router logits + top-2 (NO atomics) + fused x->bf16 --------
__global__ __launch_bounds__(256) void router_kernel(
    const float* __restrict__ x, const float* __restrict__ gw, const float* __restrict__ gb,
    int2* __restrict__ e01, float2* __restrict__ w01, unsigned short* __restrict__ xb)
{
  __shared__ float sgw[EE * DD];
  const int tid = threadIdx.x;
  for (int i = tid; i < EE * DD / 4; i += 256)
    ((float4*)sgw)[i] = ((const float4*)gw)[i];
  __syncthreads();
  const int wid = tid >> 6, l = tid & 63;
  const int t = blockIdx.x * 4 + wid;
  double acc[EE];
  #pragma unroll
  for (int e = 0; e < EE; ++e) acc[e] = 0.0;
  const float4* xr = (const float4*)(x + (size_t)t * DD);
  ushort4* xw = (ushort4*)(xb + (size_t)t * DD);
  #pragma unroll
  for (int it = 0; it < 4; ++it){
    float4 xv = xr[it * 64 + l];
    ushort4 r;
    r.x = f2b(xv.x); r.y = f2b(xv.y); r.z = f2b(xv.z); r.w = f2b(xv.w);
    xw[it * 64 + l] = r;                         // fused x -> bf16
    #pragma unroll
    for (int e = 0; e < EE; ++e){
      float4 g = ((const float4*)(sgw + e * DD))[it * 64 + l];
      acc[e] += (double)xv.x * g.x + (double)xv.y * g.y
              + (double)xv.z * g.z + (double)xv.w * g.w;
    }
  }
  #pragma unroll
  for (int off = 32; off > 0; off >>= 1){
    #pragma unroll
    for (int e = 0; e < EE; ++e) acc[e] += __shfl_xor(acc[e], off);
  }
  if (l == 0){
    float lg[EE];
    #pragma unroll
    for (int e = 0; e < EE; ++e) lg[e] = (float)acc[e] + gb[e];
    int e0 = 0; float v0 = lg[0];
    for (int e = 1; e < EE; ++e) if (lg[e] > v0){ v0 = lg[e]; e0 = e; }
    int e1 = -1; float v1 = -3.4e38f;
    for (int e = 0; e < EE; ++e) if (e != e0 && lg[e] > v1){ v1 = lg[e]; e1 = e; }
    float ex = expf(v1 - v0);            // <= 1
    float s = 1.0f + ex;
    e01[t] = make_int2(e0, e1);
    w01[t] = make_float2(1.0f / s, ex / s);
  }
}

// ---------------- phase 1b: per-expert compaction (8 blocks, LDS scan, no atomics) ------
// toks entry = tok*2 + slot (slot: 0 if e is tok's top-1, else 1) = partial-row index.
__global__ __launch_bounds__(256) void compact_kernel(
    const int2* __restrict__ e01,
    int* __restrict__ counts, int* __restrict__ toks)
{
  const int e = blockIdx.x;
  const int tid = threadIdx.x;
  __shared__ int pre[256];
  const int base = tid * (T_TOK / 256);          // 32 tokens/thread, token-ordered
  int c = 0;
  #pragma unroll 4
  for (int i = 0; i < T_TOK / 256; ++i){
    int2 ee = e01[base + i];
    c += (ee.x == e || ee.y == e) ? 1 : 0;
  }
  pre[tid] = c;
  __syncthreads();
  #pragma unroll
  for (int off = 1; off < 256; off <<= 1){
    int add = (tid >= off) ? pre[tid - off] : 0;
    __syncthreads();
    pre[tid] += add;
    __syncthreads();
  }
  int pos = pre[tid] - c;                        // exclusive prefix
  #pragma unroll 4
  for (int i = 0; i < T_TOK / 256; ++i){
    int2 ee = e01[base + i];
    if (ee.x == e || ee.y == e){
      toks[e * CAP + pos] = (base + i) * 2 + (ee.x == e ? 0 : 1);
      ++pos;
    }
  }
  if (tid == 255) counts[e] = pre[255];
}

// ---------------- phase 2: per-expert gathered GEMM -> bf16 partial rows (no atomics) ---
// 1D grid 8192, expert-chunked XCD swizzle: e = bid&7 (XCD e owns expert e),
// within expert nt-fastest -> B_e (2MB) L2-resident, A-tiles fetched once per XCD.
__global__ __launch_bounds__(256, 4) void moe_gemm(
    const unsigned short* __restrict__ xb,     // [T][D] bf16
    const unsigned short* __restrict__ wtr,    // [E][O][D] bf16 (pre-transposed)
    const int* __restrict__ counts,
    const int* __restrict__ toks,              // packed tok*2+slot
    unsigned short* __restrict__ part)         // [2T][O] bf16 raw expert outputs
{
  const int bid = blockIdx.x;
  const int e  = bid & 7;                      // XCD = bid%8 -> expert e pinned to XCD e
  const int r  = bid >> 3;                     // 0..1023, work order within expert
  const int mt = r >> 3;                       // 0..127
  const int nt = r & 7;                        // fastest: 8 consecutive share A-tile
  const int cnt = counts[e];
  if (mt * BM >= cnt) return;

  __shared__ __align__(16) unsigned short As[BM * BK];   // 8 KB
  __shared__ __align__(16) unsigned short Bs[BN * BK];   // 16 KB

  const int tid = threadIdx.x;
  const int wid = tid >> 6;
  const int l = tid & 63;
  const int lb = e * CAP;

  const unsigned short* srcA[2];
  const unsigned short* srcB[4];
  #pragma unroll
  for (int i = 0; i < 2; ++i){
    int rr = i * 32 + wid * 8 + (l >> 3);         // tile row 0..63
    int c = (l & 7) ^ (rr & 7);                   // pre-swizzled source chunk
    int gr = mt * BM + rr; if (gr > cnt - 1) gr = cnt - 1;
    int tok = toks[lb + gr] >> 1;
    srcA[i] = xb + (size_t)tok * DD + c * 8;
  }
  #pragma unroll
  for (int i = 0; i < 4; ++i){
    int rr = i * 32 + wid * 8 + (l >> 3);         // tile row 0..127
    int c = (l & 7) ^ (rr & 7);
    srcB[i] = wtr + ((size_t)e << 20) + (size_t)(nt * BN + rr) * DD + c * 8;
  }

  f32x4 acc[2][4];
  #pragma unroll
  for (int m = 0; m < 2; ++m)
    #pragma unroll
    for (int n = 0; n < 4; ++n) acc[m][n] = (f32x4)0.0f;

  const int wr = wid >> 1, wc = wid & 1;
  const int rA = l & 15, hi = l >> 4, x7 = l & 7;
  const char* AsB = (const char*)As;
  const char* BsB = (const char*)Bs;

  for (int kb = 0; kb < DD / BK; ++kb){
    __syncthreads();                              // previous compute done
    #pragma unroll
    for (int i = 0; i < 2; ++i)
      gld16(srcA[i] + kb * BK, As + (i * 32 + wid * 8) * BK);
    #pragma unroll
    for (int i = 0; i < 4; ++i)
      gld16(srcB[i] + kb * BK, Bs + (i * 32 + wid * 8) * BK);
    __syncthreads();                              // drains vmcnt before barrier
    #pragma unroll
    for (int kk = 0; kk < 2; ++kk){
      short8 af[2], bf[4];
      const int ch = ((kk << 2) + hi) ^ x7;       // swizzled read chunk
      #pragma unroll
      for (int m = 0; m < 2; ++m){
        int row = wr * 32 + m * 16 + rA;          // row&7 == l&7
        af[m] = *(const short8*)(AsB + row * (BK * 2) + ch * 16);
      }
      #pragma unroll
      for (int n = 0; n < 4; ++n){
        int orow = wc * 64 + n * 16 + rA;
        bf[n] = *(const short8*)(BsB + orow * (BK * 2) + ch * 16);
      }
      #pragma unroll
      for (int m = 0; m < 2; ++m)
        #pragma unroll
        for (int n = 0; n < 4; ++n)
          acc[m][n] = __builtin_amdgcn_mfma_f32_16x16x32_bf16(af[m], bf[n], acc[m][n], 0, 0, 0);
    }
  }

  // epilogue: plain bf16 stores of raw acc into this entry's partial row
  const int col0 = nt * BN + wc * 64;
  #pragma unroll
  for (int m = 0; m < 2; ++m){
    int rbase = mt * BM + wr * 32 + m * 16 + hi * 4;
    #pragma unroll
    for (int j = 0; j < 4; ++j){
      int rr = rbase + j;
      if (rr < cnt){
        unsigned short* prow = part + (size_t)toks[lb + rr] * OO;
        #pragma unroll
        for (int n = 0; n < 4; ++n)
          prow[col0 + n * 16 + rA] = f2b(acc[m][n][j]);
      }
    }
  }
}

// ---------------- phase 3: combine -> out[t] = w0*(p0+b[e0]) + w1*(p1+b[e1]) ----------
__global__ __launch_bounds__(256) void combine_kernel(
    const unsigned short* __restrict__ part,
    const int2* __restrict__ e01, const float2* __restrict__ w01,
    const float* __restrict__ ebias, float* __restrict__ out)
{
  const int tid = threadIdx.x;
  const int wid = tid >> 6, l = tid & 63;
  const int t = blockIdx.x * 4 + wid;
  const int2 ee = e01[t];
  const float2 ww = w01[t];
  const short8* p0 = (const short8*)(part + ((size_t)t * 2) * OO);
  const short8* p1 = (const short8*)(part + ((size_t)t * 2 + 1) * OO);
  const float4* b0 = (const float4*)(ebias + (size_t)ee.x * OO);
  const float4* b1 = (const float4*)(ebias + (size_t)ee.y * OO);
  float4* o = (float4*)(out + (size_t)t * OO);
  #pragma unroll
  for (int i = 0; i < 2; ++i){
    short8 a = p0[i * 64 + l];
    short8 b = p1[i * 64 + l];
    #pragma unroll
    for (int h = 0; h < 2; ++h){
      int cidx = (i * 64 + l) * 2 + h;
      float4 bb0 = b0[cidx], bb1 = b1[cidx];
      float4 r;
      r.x = ww.x * (b2f((unsigned short)a[h*4+0]) + bb0.x) + ww.y * (b2f((unsigned short)b[h*4+0]) + bb1.x);
      r.y = ww.x * (b2f((unsigned short)a[h*4+1]) + bb0.y) + ww.y * (b2f((unsigned short)b[h*4+1]) + bb1.y);
      r.z = ww.x * (b2f((unsigned short)a[h*4+2]) + bb0.z) + ww.y * (b2f((unsigned short)b[h*4+2]) + bb1.z);
      r.w = ww.x * (b2f((unsigned short)a[h*4+3]) + bb0.w) + ww.y * (b2f((unsigned short)b[h*4+3]) + bb1.w);
      o[cidx] = r;
    }
  }
}

extern "C" void kernel_launch(void* const* d_in, const int* in_sizes, int n_in,
                              void* d_out, int out_size, void* d_ws, size_t ws_size,
                              hipStream_t stream) {
  const float* x     = (const float*)d_in[0];
  const float* gw    = (const float*)d_in[1];
  const float* gb    = (const float*)d_in[2];
  const float* ew    = (const float*)d_in[3];
  const float* ebias = (const float*)d_in[4];
  float* out = (float*)d_out;
  char* ws = (char*)d_ws;

  // layout: [0,1K) counts | [1K..) toks, e01, w01 | 1MB: part 32MB | 33MB: xb 16MB | 49MB: wtr 16MB
  int*    counts = (int*)ws;
  int*    toks   = (int*)(ws + 1024);                          // 256 KB (packed tok*2+slot)
  int2*   e01    = (int2*)(ws + 1024 + EE * CAP * 4);          // 64 KB
  float2* w01    = (float2*)(ws + 1024 + EE * CAP * 4 + T_TOK * 8); // 64 KB
  unsigned short* part = (unsigned short*)(ws + (1 << 20));            // 32 MB
  unsigned short* xb   = (unsigned short*)(ws + (1 << 20) + ((size_t)2 * T_TOK * OO * 2)); // 16 MB
  unsigned short* wtr  = xb + (size_t)T_TOK * DD;                      // 16 MB

  transp_kernel<<<dim3(DD / 64, OO / 64, EE), 256, 0, stream>>>(ew, wtr);
  router_kernel<<<T_TOK / 4, 256, 0, stream>>>(x, gw, gb, e01, w01, xb);
  compact_kernel<<<EE, 256, 0, stream>>>(e01, counts, toks);
  moe_gemm<<<8192, 256, 0, stream>>>(xb, wtr, counts, toks, part);
  combine_kernel<<<T_TOK / 4, 256, 0, stream>>>(part, e01, w01, ebias, out);
}

// Round 12
// 104.633 us; speedup vs baseline: 1.1225x; 1.0457x over previous
//
#include <hip/hip_runtime.h>
#include <stdint.h>

#define T_TOK 8192
#define DD 1024
#define OO 1024
#define EE 8
#define CAP 8192
#define BM 64
#define BN 128
#define BK 64

typedef __attribute__((ext_vector_type(8))) short short8;
typedef __attribute__((ext_vector_type(4))) float f32x4;

__device__ __forceinline__ unsigned short f2b(float f){
  union { float f; unsigned u; } v; v.f = f;
  unsigned r = v.u + 0x7FFFu + ((v.u >> 16) & 1u);
  return (unsigned short)(r >> 16);
}
__device__ __forceinline__ float b2f(unsigned short us){
  union { unsigned u; float f; } v; v.u = ((unsigned)us) << 16; return v.f;
}

__device__ __forceinline__ void gld16(const void* g, void* l){
  __builtin_amdgcn_global_load_lds(
      (const __attribute__((address_space(1))) unsigned int*)g,
      (__attribute__((address_space(3))) unsigned int*)l,
      16, 0, 0);
}

// ---------------- prep: fused router (blocks 0..2047) + W-transpose (2048..4095) --------
// Router: logits + top-2, no atomics, fused x->bf16. Transp: 64x64 f32->bf16 tiles (G13).
// Branches read only inputs, write disjoint ws regions -> order-free.
__global__ __launch_bounds__(256) void prep_kernel(
    const float* __restrict__ x, const float* __restrict__ gw, const float* __restrict__ gb,
    const float* __restrict__ ew,
    int2* __restrict__ e01, float2* __restrict__ w01,
    unsigned short* __restrict__ xb, unsigned short* __restrict__ wt)
{
  __shared__ float smem[EE * DD];                 // 32 KB; transp aliases 17.4 KB of it
  const int tid = threadIdx.x;
  const int b = blockIdx.x;

  if (b < T_TOK / 4) {
    // ---- router ----
    for (int i = tid; i < EE * DD / 4; i += 256)
      ((float4*)smem)[i] = ((const float4*)gw)[i];
    __syncthreads();
    const int wid = tid >> 6, l = tid & 63;
    const int t = b * 4 + wid;
    double acc[EE];
    #pragma unroll
    for (int e = 0; e < EE; ++e) acc[e] = 0.0;
    const float4* xr = (const float4*)(x + (size_t)t * DD);
    ushort4* xw = (ushort4*)(xb + (size_t)t * DD);
    #pragma unroll
    for (int it = 0; it < 4; ++it){
      float4 xv = xr[it * 64 + l];
      ushort4 r;
      r.x = f2b(xv.x); r.y = f2b(xv.y); r.z = f2b(xv.z); r.w = f2b(xv.w);
      xw[it * 64 + l] = r;                       // fused x -> bf16
      #pragma unroll
      for (int e = 0; e < EE; ++e){
        float4 g = ((const float4*)(smem + e * DD))[it * 64 + l];
        acc[e] += (double)xv.x * g.x + (double)xv.y * g.y
                + (double)xv.z * g.z + (double)xv.w * g.w;
      }
    }
    #pragma unroll
    for (int off = 32; off > 0; off >>= 1){
      #pragma unroll
      for (int e = 0; e < EE; ++e) acc[e] += __shfl_xor(acc[e], off);
    }
    if (l == 0){
      float lg[EE];
      #pragma unroll
      for (int e = 0; e < EE; ++e) lg[e] = (float)acc[e] + gb[e];
      int e0 = 0; float v0 = lg[0];
      for (int e = 1; e < EE; ++e) if (lg[e] > v0){ v0 = lg[e]; e0 = e; }
      int e1 = -1; float v1 = -3.4e38f;
      for (int e = 0; e < EE; ++e) if (e != e0 && lg[e] > v1){ v1 = lg[e]; e1 = e; }
      float ex = expf(v1 - v0);          // <= 1
      float s = 1.0f + ex;
      e01[t] = make_int2(e0, e1);
      w01[t] = make_float2(1.0f / s, ex / s);
    }
  } else {
    // ---- expert_w [e][d][o] -> wt [e][o][d] bf16, 64x64 tiles ----
    float (*t64)[68] = (float(*)[68])smem;        // [64][68] = 17408 B
    const int b2 = b - T_TOK / 4;                 // 0..2047
    const int e = b2 >> 8;                        // 256 tiles per expert (16 x 16)
    const int tt = b2 & 255;
    const int dbase = (tt & 15) * 64;
    const int obase = (tt >> 4) * 64;
    const float* src = ew + ((size_t)e << 20);

    const int f4c = tid & 15;                     // float4 column: o0 = f4c*4
    const int r0  = tid >> 4;                     // row within shot
    #pragma unroll
    for (int s = 0; s < 4; ++s){
      int d = r0 + s * 16;
      float4 v = *(const float4*)(src + (size_t)(dbase + d) * OO + obase + f4c * 4);
      *(float4*)&t64[d][f4c * 4] = v;             // aligned (272B row stride)
    }
    __syncthreads();

    const int o  = tid >> 2;                      // 0..63
    const int dc = (tid & 3) * 16;                // d-chunk base
    unsigned short* dst = wt + ((size_t)e << 20) + (size_t)(obase + o) * DD + dbase + dc;
    short8 lo, hi;
    #pragma unroll
    for (int k = 0; k < 8; ++k) lo[k] = (short)f2b(t64[dc + k][o]);
    #pragma unroll
    for (int k = 0; k < 8; ++k) hi[k] = (short)f2b(t64[dc + 8 + k][o]);
    *(short8*)dst = lo;
    *(short8*)(dst + 8) = hi;
  }
}

// ---------------- phase 1b: per-expert compaction (8 blocks, LDS scan, no atomics) ------
// toks entry = tok*2 + slot (slot: 0 if e is tok's top-1, else 1) = partial-row index.
__global__ __launch_bounds__(256) void compact_kernel(
    const int2* __restrict__ e01,
    int* __restrict__ counts, int* __restrict__ toks)
{
  const int e = blockIdx.x;
  const int tid = threadIdx.x;
  __shared__ int pre[256];
  const int base = tid * (T_TOK / 256);          // 32 tokens/thread, token-ordered
  int c = 0;
  #pragma unroll 4
  for (int i = 0; i < T_TOK / 256; ++i){
    int2 ee = e01[base + i];
    c += (ee.x == e || ee.y == e) ? 1 : 0;
  }
  pre[tid] = c;
  __syncthreads();
  #pragma unroll
  for (int off = 1; off < 256; off <<= 1){
    int add = (tid >= off) ? pre[tid - off] : 0;
    __syncthreads();
    pre[tid] += add;
    __syncthreads();
  }
  int pos = pre[tid] - c;                        // exclusive prefix
  #pragma unroll 4
  for (int i = 0; i < T_TOK / 256; ++i){
    int2 ee = e01[base + i];
    if (ee.x == e || ee.y == e){
      toks[e * CAP + pos] = (base + i) * 2 + (ee.x == e ? 0 : 1);
      ++pos;
    }
  }
  if (tid == 255) counts[e] = pre[255];
}

// ---------------- phase 2: per-expert gathered GEMM -> bf16 partial rows (no atomics) ---
// 1D grid 8192, expert-chunked XCD swizzle: e = bid&7 (XCD e owns expert e),
// within expert nt-fastest -> B_e (2MB) L2-resident, A-tiles fetched once per XCD.
__global__ __launch_bounds__(256, 4) void moe_gemm(
    const unsigned short* __restrict__ xb,     // [T][D] bf16
    const unsigned short* __restrict__ wtr,    // [E][O][D] bf16 (pre-transposed)
    const int* __restrict__ counts,
    const int* __restrict__ toks,              // packed tok*2+slot
    unsigned short* __restrict__ part)         // [2T][O] bf16 raw expert outputs
{
  const int bid = blockIdx.x;
  const int e  = bid & 7;                      // XCD = bid%8 -> expert e pinned to XCD e
  const int r  = bid >> 3;                     // 0..1023, work order within expert
  const int mt = r >> 3;                       // 0..127
  const int nt = r & 7;                        // fastest: 8 consecutive share A-tile
  const int cnt = counts[e];
  if (mt * BM >= cnt) return;

  __shared__ __align__(16) unsigned short As[BM * BK];   // 8 KB
  __shared__ __align__(16) unsigned short Bs[BN * BK];   // 16 KB

  const int tid = threadIdx.x;
  const int wid = tid >> 6;
  const int l = tid & 63;
  const int lb = e * CAP;

  const unsigned short* srcA[2];
  const unsigned short* srcB[4];
  #pragma unroll
  for (int i = 0; i < 2; ++i){
    int rr = i * 32 + wid * 8 + (l >> 3);         // tile row 0..63
    int c = (l & 7) ^ (rr & 7);                   // pre-swizzled source chunk
    int gr = mt * BM + rr; if (gr > cnt - 1) gr = cnt - 1;
    int tok = toks[lb + gr] >> 1;
    srcA[i] = xb + (size_t)tok * DD + c * 8;
  }
  #pragma unroll
  for (int i = 0; i < 4; ++i){
    int rr = i * 32 + wid * 8 + (l >> 3);         // tile row 0..127
    int c = (l & 7) ^ (rr & 7);
    srcB[i] = wtr + ((size_t)e << 20) + (size_t)(nt * BN + rr) * DD + c * 8;
  }

  f32x4 acc[2][4];
  #pragma unroll
  for (int m = 0; m < 2; ++m)
    #pragma unroll
    for (int n = 0; n < 4; ++n) acc[m][n] = (f32x4)0.0f;

  const int wr = wid >> 1, wc = wid & 1;
  const int rA = l & 15, hi = l >> 4, x7 = l & 7;
  const char* AsB = (const char*)As;
  const char* BsB = (const char*)Bs;

  for (int kb = 0; kb < DD / BK; ++kb){
    __syncthreads();                              // previous compute done
    #pragma unroll
    for (int i = 0; i < 2; ++i)
      gld16(srcA[i] + kb * BK, As + (i * 32 + wid * 8) * BK);
    #pragma unroll
    for (int i = 0; i < 4; ++i)
      gld16(srcB[i] + kb * BK, Bs + (i * 32 + wid * 8) * BK);
    __syncthreads();                              // drains vmcnt before barrier
    #pragma unroll
    for (int kk = 0; kk < 2; ++kk){
      short8 af[2], bf[4];
      const int ch = ((kk << 2) + hi) ^ x7;       // swizzled read chunk
      #pragma unroll
      for (int m = 0; m < 2; ++m){
        int row = wr * 32 + m * 16 + rA;          // row&7 == l&7
        af[m] = *(const short8*)(AsB + row * (BK * 2) + ch * 16);
      }
      #pragma unroll
      for (int n = 0; n < 4; ++n){
        int orow = wc * 64 + n * 16 + rA;
        bf[n] = *(const short8*)(BsB + orow * (BK * 2) + ch * 16);
      }
      #pragma unroll
      for (int m = 0; m < 2; ++m)
        #pragma unroll
        for (int n = 0; n < 4; ++n)
          acc[m][n] = __builtin_amdgcn_mfma_f32_16x16x32_bf16(af[m], bf[n], acc[m][n], 0, 0, 0);
    }
  }

  // epilogue: plain bf16 stores of raw acc into this entry's partial row
  const int col0 = nt * BN + wc * 64;
  #pragma unroll
  for (int m = 0; m < 2; ++m){
    int rbase = mt * BM + wr * 32 + m * 16 + hi * 4;
    #pragma unroll
    for (int j = 0; j < 4; ++j){
      int rr = rbase + j;
      if (rr < cnt){
        unsigned short* prow = part + (size_t)toks[lb + rr] * OO;
        #pragma unroll
        for (int n = 0; n < 4; ++n)
          prow[col0 + n * 16 + rA] = f2b(acc[m][n][j]);
      }
    }
  }
}

// ---------------- phase 3: combine -> out[t] = w0*(p0+b[e0]) + w1*(p1+b[e1]) ----------
__global__ __launch_bounds__(256) void combine_kernel(
    const unsigned short* __restrict__ part,
    const int2* __restrict__ e01, const float2* __restrict__ w01,
    const float* __restrict__ ebias, float* __restrict__ out)
{
  const int tid = threadIdx.x;
  const int wid = tid >> 6, l = tid & 63;
  const int t = blockIdx.x * 4 + wid;
  const int2 ee = e01[t];
  const float2 ww = w01[t];
  const short8* p0 = (const short8*)(part + ((size_t)t * 2) * OO);
  const short8* p1 = (const short8*)(part + ((size_t)t * 2 + 1) * OO);
  const float4* b0 = (const float4*)(ebias + (size_t)ee.x * OO);
  const float4* b1 = (const float4*)(ebias + (size_t)ee.y * OO);
  float4* o = (float4*)(out + (size_t)t * OO);
  #pragma unroll
  for (int i = 0; i < 2; ++i){
    short8 a = p0[i * 64 + l];
    short8 b = p1[i * 64 + l];
    #pragma unroll
    for (int h = 0; h < 2; ++h){
      int cidx = (i * 64 + l) * 2 + h;
      float4 bb0 = b0[cidx], bb1 = b1[cidx];
      float4 r;
      r.x = ww.x * (b2f((unsigned short)a[h*4+0]) + bb0.x) + ww.y * (b2f((unsigned short)b[h*4+0]) + bb1.x);
      r.y = ww.x * (b2f((unsigned short)a[h*4+1]) + bb0.y) + ww.y * (b2f((unsigned short)b[h*4+1]) + bb1.y);
      r.z = ww.x * (b2f((unsigned short)a[h*4+2]) + bb0.z) + ww.y * (b2f((unsigned short)b[h*4+2]) + bb1.z);
      r.w = ww.x * (b2f((unsigned short)a[h*4+3]) + bb0.w) + ww.y * (b2f((unsigned short)b[h*4+3]) + bb1.w);
      o[cidx] = r;
    }
  }
}

extern "C" void kernel_launch(void* const* d_in, const int* in_sizes, int n_in,
                              void* d_out, int out_size, void* d_ws, size_t ws_size,
                              hipStream_t stream) {
  const float* x     = (const float*)d_in[0];
  const float* gw    = (const float*)d_in[1];
  const float* gb    = (const float*)d_in[2];
  const float* ew    = (const float*)d_in[3];
  const float* ebias = (const float*)d_in[4];
  float* out = (float*)d_out;
  char* ws = (char*)d_ws;

  // layout: [0,1K) counts | [1K..) toks, e01, w01 | 1MB: part 32MB | 33MB: xb 16MB | 49MB: wtr 16MB
  int*    counts = (int*)ws;
  int*    toks   = (int*)(ws + 1024);                          // 256 KB (packed tok*2+slot)
  int2*   e01    = (int2*)(ws + 1024 + EE * CAP * 4);          // 64 KB
  float2* w01    = (float2*)(ws + 1024 + EE * CAP * 4 + T_TOK * 8); // 64 KB
  unsigned short* part = (unsigned short*)(ws + (1 << 20));            // 32 MB
  unsigned short* xb   = (unsigned short*)(ws + (1 << 20) + ((size_t)2 * T_TOK * OO * 2)); // 16 MB
  unsigned short* wtr  = xb + (size_t)T_TOK * DD;                      // 16 MB

  prep_kernel<<<T_TOK / 4 + 2048, 256, 0, stream>>>(x, gw, gb, ew, e01, w01, xb, wtr);
  compact_kernel<<<EE, 256, 0, stream>>>(e01, counts, toks);
  moe_gemm<<<8192, 256, 0, stream>>>(xb, wtr, counts, toks, part);
  combine_kernel<<<T_TOK / 4, 256, 0, stream>>>(part, e01, w01, ebias, out);
}